// Round 2
// baseline (468.213 us; speedup 1.0000x reference)
//
#include <hip/hip_runtime.h>
#include <stdint.h>

// Problem constants
#define NIMG   32
#define CCH    256
#define WDIM   56
#define HW     3136          // 56*56
#define MTOT   (NIMG*HW)     // 100352 = 784 * 128
#define KCTOT  36            // 4 ci-chunks * 9 taps
#define BK     64

typedef __attribute__((ext_vector_type(8))) short    bf16x8;
typedef __attribute__((ext_vector_type(4))) float    f32x4;
typedef __attribute__((ext_vector_type(4))) uint32_t u32x4;

// ---------------- prepass: dequantize weights -> bf16, layout [co][kc][cil] ----------------
__global__ __launch_bounds__(256) void dequant_weights(
    const int* __restrict__ widx, const float* __restrict__ lut,
    uint16_t* __restrict__ Bw) {
  int idx = blockIdx.x * 256 + threadIdx.x;        // < 256*36*64 = 589824
  int co  = idx / (KCTOT * BK);
  int r   = idx - co * (KCTOT * BK);
  int kc  = r >> 6;
  int cil = r & 63;
  int cc  = kc / 9;
  int tap = kc - cc * 9;
  int ci  = cc * 64 + cil;
  int wv  = widx[(co * CCH + ci) * 9 + tap];
  uint32_t b  = __float_as_uint(lut[wv]);
  uint32_t rn = (b + 0x7fffu + ((b >> 16) & 1u)) >> 16;   // RN-even to bf16
  Bw[idx] = (uint16_t)rn;
}

// ---------------- main: implicit-GEMM conv, halo-A + reg-double-buffered global-B ----------------
// Tap loop has NO barriers; B frags for tap t+1 are loaded while tap t's MFMAs run,
// A ks=0 frags are prefetched one tap ahead, ks=1 ds_reads hide under the ks=0 MFMA cluster.
__global__ __launch_bounds__(256, 2) void conv_mfma(
    const float* __restrict__ in, const uint16_t* __restrict__ Bw,
    const float* __restrict__ bias, float* __restrict__ out) {

  // rows 0..255: halo tile, row r holds g = m0 + r - 58 (clamped), 64 bf16 channels.
  // row 256: zeros (masked-out fragment reads land here). Row stride 144 B.
  __shared__ __align__(16) uint16_t A_lds[257 * 72];   // 37.0 KB

  const int t    = threadIdx.x;
  const int lane = t & 63;
  const int wv   = t >> 6;          // wave 0..3
  const int wm   = wv & 1;          // wave m-tile (0..1)
  const int wn   = wv >> 1;         // wave n-tile (0..1)
  const int lrow = lane & 15;
  const int kgrp = lane >> 4;       // 0..3

  const int m0  = blockIdx.x * 128;
  const int co0 = blockIdx.y * 128;

  // ---- B per-lane pointers (one per ni subtile) ----
  const uint16_t* bp[4];
#pragma unroll
  for (int ni = 0; ni < 4; ++ni)
    bp[ni] = Bw + (size_t)(co0 + wn * 64 + ni * 16 + lrow) * (KCTOT * BK) + kgrp * 8;

  // ---- prologue: issue B loads for kc=0 immediately (overlap with A staging) ----
  bf16x8 bb[2][2][4];               // [parity][ks][ni]
#pragma unroll
  for (int ks = 0; ks < 2; ++ks)
#pragma unroll
    for (int ni = 0; ni < 4; ++ni)
      bb[0][ks][ni] = *(const bf16x8*)(bp[ni] + ks * 32);

  // zero row init (visible after the first staging barrier)
  if (t < 9) *(u32x4*)((uint8_t*)A_lds + 256 * 144 + t * 16) = (u32x4){0u, 0u, 0u, 0u};

  // staging geometry: 256 threads x 8 iters cover 256 rows x 8 channel-groups
  const int st_r   = t & 31;        // + 32*i -> row
  const int st_grp = t >> 5;        // 0..7 channel-group (8 ch each)

  // per-lane (h,w) of the 4 m-rows this lane's A-fragments cover (for tap masking)
  int hh[4], ww[4], arb[4];
#pragma unroll
  for (int mi = 0; mi < 4; ++mi) {
    const int m = m0 + wm * 64 + mi * 16 + lrow;
    const int n = m / HW;
    const int s = m - n * HW;
    hh[mi] = s / WDIM;
    ww[mi] = s - hh[mi] * WDIM;
    arb[mi] = (wm * 64 + mi * 16 + lrow + 58) * 144 + kgrp * 16;  // byte base in A_lds
  }
  const int zoff = 256 * 144 + kgrp * 16;   // zero-row read address

  f32x4 acc[4][4];
#pragma unroll
  for (int i = 0; i < 4; ++i)
#pragma unroll
    for (int j = 0; j < 4; ++j)
      acc[i][j] = (f32x4){0.f, 0.f, 0.f, 0.f};

  bf16x8 aa0[2][4];                 // double-buffered ks=0 A frags
  int    aaddr[2][4];               // their byte addresses (for the ks=1 read)

#pragma unroll 1
  for (int cc = 0; cc < 4; ++cc) {
    if (cc) __syncthreads();   // protect A_lds until all waves finished previous chunk

    // ---- stage A halo: fp32 gather -> bf16 truncate-pack -> ds_write_b128 ----
#pragma unroll
    for (int i = 0; i < 8; ++i) {
      const int r = st_r + 32 * i;
      long g = (long)m0 + r - 58;
      g = g < 0 ? 0 : (g >= MTOT ? (MTOT - 1) : g);   // clamp; clamped rows masked at use
      const int n = (int)((unsigned long)g / HW);
      const int s = (int)(g - (long)n * HW);
      const float* p = in + (size_t)n * (CCH * HW) + (size_t)(cc * 64 + st_grp * 8) * HW + s;
      u32x4 pk;
#pragma unroll
      for (int jj = 0; jj < 4; ++jj) {
        const uint32_t b0 = __float_as_uint(p[(size_t)(2 * jj) * HW]);
        const uint32_t b1 = __float_as_uint(p[(size_t)(2 * jj + 1) * HW]);
        pk[jj] = (b0 >> 16) | (b1 & 0xffff0000u);     // truncate-to-bf16 pack
      }
      *(u32x4*)((uint8_t*)A_lds + r * 144 + st_grp * 16) = pk;
    }
    __syncthreads();

    // ---- tap-0 ks=0 A frags (exposed once per chunk, unavoidable: LDS just changed) ----
#pragma unroll
    for (int mi = 0; mi < 4; ++mi) {
      const bool v0 = (((unsigned)(hh[mi] - 1)) < 56u) & (((unsigned)(ww[mi] - 1)) < 56u);
      const int ad = v0 ? (arb[mi] - 57 * 144) : zoff;   // tap 0: d = -57
      aaddr[0][mi] = ad;
      aa0[0][mi] = *(const bf16x8*)((const uint8_t*)A_lds + ad);
    }

    // ---- 9 taps, fully unrolled, software-pipelined, NO barriers ----
#pragma unroll
    for (int tap = 0; tap < 9; ++tap) {
      const int cur = tap & 1;
      const int nxt = cur ^ 1;

      // 1) B prefetch for next kc (into bb[nxt])
      if (tap < 8) {
#pragma unroll
        for (int ks = 0; ks < 2; ++ks)
#pragma unroll
          for (int ni = 0; ni < 4; ++ni)
            bb[nxt][ks][ni] = *(const bf16x8*)(bp[ni] + (tap + 1) * BK + ks * 32);
      } else {
        // prefetch next chunk's kc (cc+1, tap 0); dummy re-read for the last chunk
#pragma unroll
        for (int ni = 0; ni < 4; ++ni) {
          const uint16_t* pn = (cc < 3) ? (bp[ni] + 9 * BK) : bp[ni];
#pragma unroll
          for (int ks = 0; ks < 2; ++ks)
            bb[nxt][ks][ni] = *(const bf16x8*)(pn + ks * 32);
        }
      }

      // 2) A ks=0 prefetch for next tap (into aa0[nxt])
      if (tap < 8) {
        const int kh2 = (tap + 1) / 3;
        const int dh2 = kh2 - 1;
        const int dw2 = (tap + 1 - kh2 * 3) - 1;
        const int d2  = dh2 * WDIM + dw2;
#pragma unroll
        for (int mi = 0; mi < 4; ++mi) {
          const bool v = (((unsigned)(hh[mi] + dh2)) < 56u) &
                         (((unsigned)(ww[mi] + dw2)) < 56u);
          const int ad = v ? (arb[mi] + d2 * 144) : zoff;
          aaddr[nxt][mi] = ad;
          aa0[nxt][mi] = *(const bf16x8*)((const uint8_t*)A_lds + ad);
        }
      }

      // 3) A ks=1 frags for current tap (latency hidden under ks=0 MFMA cluster)
      bf16x8 a1[4];
#pragma unroll
      for (int mi = 0; mi < 4; ++mi)
        a1[mi] = *(const bf16x8*)((const uint8_t*)A_lds + aaddr[cur][mi] + 64);

      // 4) MFMAs: ks=0 cluster then ks=1 cluster
      __builtin_amdgcn_s_setprio(1);
#pragma unroll
      for (int mi = 0; mi < 4; ++mi)
#pragma unroll
        for (int ni = 0; ni < 4; ++ni)
          acc[mi][ni] = __builtin_amdgcn_mfma_f32_16x16x32_bf16(
              aa0[cur][mi], bb[cur][0][ni], acc[mi][ni], 0, 0, 0);
#pragma unroll
      for (int mi = 0; mi < 4; ++mi)
#pragma unroll
        for (int ni = 0; ni < 4; ++ni)
          acc[mi][ni] = __builtin_amdgcn_mfma_f32_16x16x32_bf16(
              a1[mi], bb[cur][1][ni], acc[mi][ni], 0, 0, 0);
      __builtin_amdgcn_s_setprio(0);
    }

    // carry: tap 8 prefetched next chunk's tap-0 frags into bb[1]; next chunk reads bb[0]
#pragma unroll
    for (int ks = 0; ks < 2; ++ks)
#pragma unroll
      for (int ni = 0; ni < 4; ++ni)
        bb[0][ks][ni] = bb[1][ks][ni];
    if (cc < 3) {
#pragma unroll
      for (int ni = 0; ni < 4; ++ni) bp[ni] += 9 * BK;   // advance one ci-chunk
    }
  }

  // ---- epilogue: add bias, store (D: row=(lane>>4)*4+r, col=lane&15) ----
  float bv[4];
#pragma unroll
  for (int ni = 0; ni < 4; ++ni)
    bv[ni] = bias[co0 + wn * 64 + ni * 16 + lrow];

#pragma unroll
  for (int mi = 0; mi < 4; ++mi) {
#pragma unroll
    for (int r = 0; r < 4; ++r) {
      const int mrow = m0 + wm * 64 + mi * 16 + kgrp * 4 + r;
      const int ni_img = mrow / HW;
      const int ss = mrow - ni_img * HW;
      float* ob = out + (size_t)ni_img * (CCH * HW) + ss;
#pragma unroll
      for (int ni = 0; ni < 4; ++ni) {
        const int co = co0 + wn * 64 + ni * 16 + lrow;
        ob[(size_t)co * HW] = acc[mi][ni][r] + bv[ni];
      }
    }
  }
}

extern "C" void kernel_launch(void* const* d_in, const int* in_sizes, int n_in,
                              void* d_out, int out_size, void* d_ws, size_t ws_size,
                              hipStream_t stream) {
  const float* in   = (const float*)d_in[0];
  const int*   widx = (const int*)d_in[1];
  const float* lut  = (const float*)d_in[2];
  const float* bias = (const float*)d_in[3];
  float* out = (float*)d_out;
  uint16_t* Bw = (uint16_t*)d_ws;   // 589824 * 2 B = 1.18 MB scratch

  dequant_weights<<<dim3(589824 / 256), dim3(256), 0, stream>>>(widx, lut, Bw);
  conv_mfma<<<dim3(MTOT / 128, CCH / 128), dim3(256), 0, stream>>>(in, Bw, bias, out);
}

// Round 3
// 366.367 us; speedup vs baseline: 1.2780x; 1.2780x over previous
//
#include <hip/hip_runtime.h>
#include <stdint.h>

// Problem constants
#define NIMG   32
#define CCH    256
#define WDIM   56
#define HW     3136          // 56*56
#define MTOT   (NIMG*HW)     // 100352 = 784 * 128
#define KCTOT  36            // 4 ci-chunks * 9 taps
#define BK     64

typedef __attribute__((ext_vector_type(8))) short    bf16x8;
typedef __attribute__((ext_vector_type(4))) float    f32x4;
typedef __attribute__((ext_vector_type(4))) uint32_t u32x4;

typedef __attribute__((address_space(1))) const uint8_t* as1cp;
typedef __attribute__((address_space(3))) uint8_t*       as3p;

// ---------------- prepass: dequantize weights -> bf16, layout [co][kc][cil] ----------------
__global__ __launch_bounds__(256) void dequant_weights(
    const int* __restrict__ widx, const float* __restrict__ lut,
    uint16_t* __restrict__ Bw) {
  int idx = blockIdx.x * 256 + threadIdx.x;        // < 256*36*64 = 589824
  int co  = idx / (KCTOT * BK);
  int r   = idx - co * (KCTOT * BK);
  int kc  = r >> 6;
  int cil = r & 63;
  int cc  = kc / 9;
  int tap = kc - cc * 9;
  int ci  = cc * 64 + cil;
  int wv  = widx[(co * CCH + ci) * 9 + tap];
  uint32_t b  = __float_as_uint(lut[wv]);
  uint32_t rn = (b + 0x7fffu + ((b >> 16) & 1u)) >> 16;   // RN-even to bf16
  Bw[idx] = (uint16_t)rn;
}

// ---------------- main: halo-A (per chunk) + LDS double-buffered B with counted vmcnt ----------------
// Per tap: issue next tap's B stage (global_load_lds, 4 ops/thread), s_waitcnt vmcnt(4)
// (wait ONLY the previous stage; keep 4 in flight across both barriers), raw s_barrier,
// ds_read frags, 32 MFMAs, raw s_barrier. vmcnt never drains to 0 in the main loop.
__global__ __launch_bounds__(256, 2) void conv_mfma(
    const float* __restrict__ in, const uint16_t* __restrict__ Bw,
    const float* __restrict__ bias, float* __restrict__ out) {

  // A: rows 0..255 halo (row r holds g = m0 + r - 58), row 256 = zeros.
  // Row stride 144 B -> bank-quad (r+g)%8, 2-way on 16-lane reads = free.
  __shared__ __align__(16) uint16_t A_lds[257 * 72];          // 37.0 KB
  // B: two 16 KB buffers, [co_l][granule] with granule ck stored at ck^(co_l&7).
  __shared__ __align__(16) uint16_t B_lds[2 * 128 * 64];      // 32 KB

  const int t    = threadIdx.x;
  const int lane = t & 63;
  const int wv   = t >> 6;          // wave 0..3
  const int wm   = wv & 1;          // wave m-tile (0..1)
  const int wn   = wv >> 1;         // wave n-tile (0..1)
  const int lrow = lane & 15;
  const int kgrp = lane >> 4;       // 0..3

  const int m0  = blockIdx.x * 128;
  const int co0 = blockIdx.y * 128;

  // B staging lane constants (wave stages its own 32 co rows; granule source pre-swizzled)
  const int b_row8 = lane >> 3;     // 0..7 row within 8-row segment
  const int b_g    = lane & 7;      // dest granule position

  // ---- issue B stage for kc=0 into buf0 immediately (overlaps A gather) ----
#pragma unroll
  for (int c = 0; c < 4; ++c) {
    const int co_l = wv * 32 + c * 8 + b_row8;
    const int ck   = b_g ^ (co_l & 7);
    const uint8_t* gsrc = (const uint8_t*)(Bw + ((size_t)(co0 + co_l) * KCTOT + 0) * BK) + ck * 16;
    as3p ldst = (as3p)((uint8_t*)B_lds + (wv * 32 + c * 8) * 128);
    __builtin_amdgcn_global_load_lds((as1cp)gsrc, ldst, 16, 0, 0);
  }

  // zero row init
  if (t < 9) *(u32x4*)((uint8_t*)A_lds + 256 * 144 + t * 16) = (u32x4){0u, 0u, 0u, 0u};

  // A staging geometry: 256 threads x 8 iters cover 256 rows x 8 channel-groups
  const int st_r   = t & 31;
  const int st_grp = t >> 5;

  // per-lane (h,w) and LDS byte base of the 4 m-rows this lane's A-frags cover
  int hh[4], ww[4], arb[4];
#pragma unroll
  for (int mi = 0; mi < 4; ++mi) {
    const int m = m0 + wm * 64 + mi * 16 + lrow;
    const int n = m / HW;
    const int s = m - n * HW;
    hh[mi] = s / WDIM;
    ww[mi] = s - hh[mi] * WDIM;
    arb[mi] = (wm * 64 + mi * 16 + lrow + 58) * 144 + kgrp * 16;
  }
  const int zoff = 256 * 144 + kgrp * 16;

  f32x4 acc[4][4];
#pragma unroll
  for (int i = 0; i < 4; ++i)
#pragma unroll
    for (int j = 0; j < 4; ++j)
      acc[i][j] = (f32x4){0.f, 0.f, 0.f, 0.f};

#pragma unroll 1
  for (int cc = 0; cc < 4; ++cc) {
    // ---- stage A halo: fp32 gather -> bf16 pack -> ds_write_b128 ----
    // (its load-waits also drain the older chunk-crossing B stage - harmless)
#pragma unroll
    for (int i = 0; i < 8; ++i) {
      const int r = st_r + 32 * i;
      long g = (long)m0 + r - 58;
      g = g < 0 ? 0 : (g >= MTOT ? (MTOT - 1) : g);
      const int n = (int)((unsigned long)g / HW);
      const int s = (int)(g - (long)n * HW);
      const float* p = in + (size_t)n * (CCH * HW) + (size_t)(cc * 64 + st_grp * 8) * HW + s;
      u32x4 pk;
#pragma unroll
      for (int jj = 0; jj < 4; ++jj) {
        const uint32_t b0 = __float_as_uint(p[(size_t)(2 * jj) * HW]);
        const uint32_t b1 = __float_as_uint(p[(size_t)(2 * jj + 1) * HW]);
        pk[jj] = (b0 >> 16) | (b1 & 0xffff0000u);
      }
      *(u32x4*)((uint8_t*)A_lds + r * 144 + st_grp * 16) = pk;
    }
    asm volatile("s_waitcnt lgkmcnt(0)" ::: "memory");
    __builtin_amdgcn_sched_barrier(0);
    __builtin_amdgcn_s_barrier();
    __builtin_amdgcn_sched_barrier(0);

    const int scc = (cc & 1) << 14;   // read-buffer byte offset parity component

#pragma unroll
    for (int tap = 0; tap < 9; ++tap) {
      const int kc    = cc * 9 + tap;
      const int rdoff = (tap & 1) ? (scc ^ 16384) : scc;   // buf[kc&1]
      const int wroff = rdoff ^ 16384;
      // tap<8: next tap; tap==8: next chunk's tap 0; last tap of all: dummy re-stage
      const int kc_next = (tap < 8 || cc < 3) ? kc + 1 : kc;

      // ---- issue B stage for kc_next (4 x global_load_lds, stays in flight) ----
#pragma unroll
      for (int c = 0; c < 4; ++c) {
        const int co_l = wv * 32 + c * 8 + b_row8;
        const int ck   = b_g ^ (co_l & 7);
        const uint8_t* gsrc =
            (const uint8_t*)(Bw + ((size_t)(co0 + co_l) * KCTOT + kc_next) * BK) + ck * 16;
        as3p ldst = (as3p)((uint8_t*)B_lds + wroff + (wv * 32 + c * 8) * 128);
        __builtin_amdgcn_global_load_lds((as1cp)gsrc, ldst, 16, 0, 0);
      }
      __builtin_amdgcn_sched_barrier(0);
      asm volatile("s_waitcnt vmcnt(4)" ::: "memory");  // retire stage(kc); keep stage(kc_next)
      __builtin_amdgcn_sched_barrier(0);
      __builtin_amdgcn_s_barrier();
      __builtin_amdgcn_sched_barrier(0);

      // ---- frag reads ----
      const int kh = tap / 3;
      const int dh = kh - 1;
      const int dw = (tap - kh * 3) - 1;
      const int d  = dh * WDIM + dw;

      bf16x8 af[2][4], bfb[2][4];
#pragma unroll
      for (int mi = 0; mi < 4; ++mi) {
        const bool valid = (((unsigned)(hh[mi] + dh)) < 56u) & (((unsigned)(ww[mi] + dw)) < 56u);
        const int ad = valid ? (arb[mi] + d * 144) : zoff;
        af[0][mi] = *(const bf16x8*)((const uint8_t*)A_lds + ad);
        af[1][mi] = *(const bf16x8*)((const uint8_t*)A_lds + ad + 64);
      }
#pragma unroll
      for (int ks = 0; ks < 2; ++ks)
#pragma unroll
        for (int ni = 0; ni < 4; ++ni) {
          const int nrow = wn * 64 + ni * 16 + lrow;
          const int gran = ((ks * 4 + kgrp) ^ (lrow & 7)) * 16;   // undo storage swizzle
          bfb[ks][ni] = *(const bf16x8*)((const uint8_t*)B_lds + rdoff + nrow * 128 + gran);
        }

      __builtin_amdgcn_s_setprio(1);
#pragma unroll
      for (int mi = 0; mi < 4; ++mi)
#pragma unroll
        for (int ni = 0; ni < 4; ++ni)
          acc[mi][ni] = __builtin_amdgcn_mfma_f32_16x16x32_bf16(
              af[0][mi], bfb[0][ni], acc[mi][ni], 0, 0, 0);
#pragma unroll
      for (int mi = 0; mi < 4; ++mi)
#pragma unroll
        for (int ni = 0; ni < 4; ++ni)
          acc[mi][ni] = __builtin_amdgcn_mfma_f32_16x16x32_bf16(
              af[1][mi], bfb[1][ni], acc[mi][ni], 0, 0, 0);
      __builtin_amdgcn_s_setprio(0);

      __builtin_amdgcn_sched_barrier(0);
      __builtin_amdgcn_s_barrier();
      __builtin_amdgcn_sched_barrier(0);
    }
  }

  // ---- epilogue: add bias, store (D: row=(lane>>4)*4+r, col=lane&15) ----
  float bv[4];
#pragma unroll
  for (int ni = 0; ni < 4; ++ni)
    bv[ni] = bias[co0 + wn * 64 + ni * 16 + lrow];

#pragma unroll
  for (int mi = 0; mi < 4; ++mi) {
#pragma unroll
    for (int r = 0; r < 4; ++r) {
      const int mrow = m0 + wm * 64 + mi * 16 + kgrp * 4 + r;
      const int ni_img = mrow / HW;
      const int ss = mrow - ni_img * HW;
      float* ob = out + (size_t)ni_img * (CCH * HW) + ss;
#pragma unroll
      for (int ni = 0; ni < 4; ++ni) {
        const int co = co0 + wn * 64 + ni * 16 + lrow;
        ob[(size_t)co * HW] = acc[mi][ni][r] + bv[ni];
      }
    }
  }
}

extern "C" void kernel_launch(void* const* d_in, const int* in_sizes, int n_in,
                              void* d_out, int out_size, void* d_ws, size_t ws_size,
                              hipStream_t stream) {
  const float* in   = (const float*)d_in[0];
  const int*   widx = (const int*)d_in[1];
  const float* lut  = (const float*)d_in[2];
  const float* bias = (const float*)d_in[3];
  float* out = (float*)d_out;
  uint16_t* Bw = (uint16_t*)d_ws;   // 589824 * 2 B = 1.18 MB scratch

  dequant_weights<<<dim3(589824 / 256), dim3(256), 0, stream>>>(widx, lut, Bw);
  conv_mfma<<<dim3(MTOT / 128, CCH / 128), dim3(256), 0, stream>>>(in, Bw, bias, out);
}